// Round 3
// baseline (519.961 us; speedup 1.0000x reference)
//
#include <hip/hip_runtime.h>
#include <math.h>

// Problem constants (fixed by reference)
#define Bb 8
#define Nn 1024
#define Mm 1024
#define Dd 256
#define Hh 4
#define Pp 128
// C = 64, scale = 1/sqrt(64) = 0.125 (folded into Q at projection time)

using f16x8 = __attribute__((ext_vector_type(8))) _Float16;
using f32x4 = __attribute__((ext_vector_type(4))) float;
using i32x4 = __attribute__((ext_vector_type(4))) int;

#define MFMA16(a, b, c) __builtin_amdgcn_mfma_f32_16x16x32_f16(a, b, c, 0, 0, 0)

// XOR-swizzled byte offset into a row-major [R][64] f16 tile (128B rows).
__device__ __forceinline__ int swz(int row, int colByte) {
    return row * 128 + (colByte ^ ((row & 7) << 4));
}

__device__ __forceinline__ f16x8 cvt8(f32x4 a, f32x4 b) {
    f16x8 h;
    h[0] = (_Float16)a[0]; h[1] = (_Float16)a[1]; h[2] = (_Float16)a[2]; h[3] = (_Float16)a[3];
    h[4] = (_Float16)b[0]; h[5] = (_Float16)b[1]; h[6] = (_Float16)b[2]; h[7] = (_Float16)b[3];
    return h;
}

// Load 8 consecutive f32 from global, convert to f16, store one 16B LDS slot.
__device__ __forceinline__ void stage8_f32(const float* __restrict__ g, unsigned char* dst) {
    f32x4 a = *(const f32x4*)g;
    f32x4 b = *(const f32x4*)(g + 4);
    *(f16x8*)dst = cvt8(a, b);
}

// ---------------------------------------------------------------------------
// Kernel 1: fused QKV projection, 128x64 output tile, reg-prefetched K-loop.
// z = 0 -> Q, PRE-SCALED by 0.125 (row-major f16 [8192][256])
// z = 1 -> K (row-major f16 [8192][256])
// z = 2 -> V, written TRANSPOSED per (b,h): Vt[((b*H+h)*64 + c)][1024 m] f16
// ---------------------------------------------------------------------------
__global__ __launch_bounds__(256, 3) void proj_kernel(
    const float* __restrict__ xq, const float* __restrict__ xk, const float* __restrict__ xv,
    const float* __restrict__ wq, const float* __restrict__ wk, const float* __restrict__ wv,
    const float* __restrict__ bq, const float* __restrict__ bk, const float* __restrict__ bv,
    _Float16* __restrict__ Qo, _Float16* __restrict__ Ko, _Float16* __restrict__ Vt)
{
    __shared__ __align__(16) unsigned char smem[24576];
    unsigned char* aT = smem;           // [128][64] f16, swizzled (16384B)
    unsigned char* bT = smem + 16384;   // [64][64]  f16, swizzled (8192B)

    const int z = blockIdx.z;
    const float* X    = (z == 0) ? xq : (z == 1) ? xk : xv;
    const float* W    = (z == 0) ? wq : (z == 1) ? wk : wv;
    const float* bias = (z == 0) ? bq : (z == 1) ? bk : bv;

    const int r0 = blockIdx.x * 128;  // global row tile (r = b*1024 + token)
    const int c0 = blockIdx.y * 64;   // output-col tile (= head h * 64)
    const int l = threadIdx.x;
    const int lane = l & 63;
    const int w = l >> 6;             // wave id 0..3 (owns rows w*32..w*32+31)
    const int grp = lane >> 4, col16 = lane & 15;

    float bs[4];
#pragma unroll
    for (int t = 0; t < 4; ++t) bs[t] = bias[c0 + t * 16 + col16];

    f32x4 acc[2][4] = {};
    f32x4 aR[4][2], bR[2][2];

#define PROJ_LOAD(kc_) { \
    for (int it = 0; it < 4; ++it) { \
        int s = l + it * 256, row = s >> 3, sl = s & 7; \
        const float* g = X + (size_t)(r0 + row) * Dd + (kc_) * 64 + sl * 8; \
        aR[it][0] = *(const f32x4*)g; aR[it][1] = *(const f32x4*)(g + 4); \
    } \
    for (int it = 0; it < 2; ++it) { \
        int s = l + it * 256, row = s >> 3, sl = s & 7; \
        const float* g = W + (size_t)(c0 + row) * Dd + (kc_) * 64 + sl * 8; \
        bR[it][0] = *(const f32x4*)g; bR[it][1] = *(const f32x4*)(g + 4); \
    } }

#define PROJ_WRITE() { \
    for (int it = 0; it < 4; ++it) { \
        int s = l + it * 256, row = s >> 3, sl = s & 7; \
        *(f16x8*)(aT + swz(row, sl * 16)) = cvt8(aR[it][0], aR[it][1]); \
    } \
    for (int it = 0; it < 2; ++it) { \
        int s = l + it * 256, row = s >> 3, sl = s & 7; \
        *(f16x8*)(bT + swz(row, sl * 16)) = cvt8(bR[it][0], bR[it][1]); \
    } }

#define PROJ_COMPUTE() { \
    __builtin_amdgcn_s_setprio(1); \
    _Pragma("unroll") for (int rf = 0; rf < 2; ++rf) { \
        int arow = w * 32 + rf * 16 + col16; \
        f16x8 a0 = *(const f16x8*)(aT + swz(arow, grp * 16)); \
        f16x8 a1 = *(const f16x8*)(aT + swz(arow, grp * 16 + 64)); \
        _Pragma("unroll") for (int t = 0; t < 4; ++t) { \
            int brow = t * 16 + col16; \
            f16x8 b0 = *(const f16x8*)(bT + swz(brow, grp * 16)); \
            f16x8 b1 = *(const f16x8*)(bT + swz(brow, grp * 16 + 64)); \
            acc[rf][t] = MFMA16(a0, b0, acc[rf][t]); \
            acc[rf][t] = MFMA16(a1, b1, acc[rf][t]); \
        } \
    } \
    __builtin_amdgcn_s_setprio(0); }

    PROJ_LOAD(0);
    PROJ_WRITE();
    __syncthreads();
    for (int kc = 0; kc < 3; ++kc) {
        PROJ_LOAD(kc + 1);
        PROJ_COMPUTE();
        __syncthreads();
        PROJ_WRITE();
        __syncthreads();
    }
    PROJ_COMPUTE();
    __syncthreads();   // before LDS overlay in epilogue

    if (z < 2) {
        _Float16* O = (z == 0) ? Qo : Ko;
        const float osc = (z == 0) ? 0.125f : 1.0f;
        _Float16* oT = (_Float16*)smem;            // [128][72] f16 overlay (18432B)
#pragma unroll
        for (int rf = 0; rf < 2; ++rf)
#pragma unroll
            for (int t = 0; t < 4; ++t)
#pragma unroll
                for (int j = 0; j < 4; ++j) {
                    int r = w * 32 + rf * 16 + grp * 4 + j;
                    oT[r * 72 + t * 16 + col16] = (_Float16)((acc[rf][t][j] + bs[t]) * osc);
                }
        __syncthreads();
        const int row = l >> 1, half = l & 1;
        const _Float16* src = oT + row * 72 + half * 32;
        _Float16* dst = O + (size_t)(r0 + row) * Dd + c0 + half * 32;
#pragma unroll
        for (int s = 0; s < 4; ++s)
            *(f16x8*)(dst + s * 8) = *(const f16x8*)(src + s * 8);
    } else {
        _Float16* vt = (_Float16*)smem;            // [64 c][136 m] f16 overlay (17408B)
#pragma unroll
        for (int rf = 0; rf < 2; ++rf)
#pragma unroll
            for (int t = 0; t < 4; ++t)
#pragma unroll
                for (int j = 0; j < 4; ++j) {
                    int r = w * 32 + rf * 16 + grp * 4 + j;   // local m
                    int c = t * 16 + col16;                   // local channel
                    vt[c * 136 + r] = (_Float16)(acc[rf][t][j] + bs[t]);
                }
        __syncthreads();
        const int bo = r0 >> 10, m0 = r0 & 1023, h = blockIdx.y;
        const int c = l >> 2, q = l & 3;
        const _Float16* src = vt + c * 136 + q * 32;
        _Float16* dst = Vt + (size_t)((bo * Hh + h) * 64 + c) * Mm + m0 + q * 32;
#pragma unroll
        for (int s = 0; s < 4; ++s)
            *(f16x8*)(dst + s * 8) = *(const f16x8*)(src + s * 8);
    }
#undef PROJ_LOAD
#undef PROJ_WRITE
#undef PROJ_COMPUTE
}

// ---------------------------------------------------------------------------
// Kernel 2: fused LRPE attention.  One block = 64 query rows of one (b, h),
// 512 threads = 8 waves: wave (wrow, mhalf) owns q-rows wrow*16..+15 and
// m-columns mhalf*32..+31 of each 64-m tile.  Two passes, no-max softmax,
// 2-deep register prefetch of K/V/af/eidx.
// LDS (63744B): Uk 8K | Uv 8K | Up 8K | spL [64][136]f16 | afT [64][68]f32
//               | eiT [64][68]u8
// ---------------------------------------------------------------------------
__global__ __launch_bounds__(512, 4) void attn_kernel(
    const _Float16* __restrict__ Qi, const _Float16* __restrict__ Ki,
    const _Float16* __restrict__ Vt, const float* __restrict__ emb,
    const float* __restrict__ afac, const int* __restrict__ eidx,
    const unsigned char* __restrict__ kmask,
    float* __restrict__ hid, float* __restrict__ attn)
{
    __shared__ __align__(16) unsigned char smem[63744];
    unsigned char* Uk = smem;
    unsigned char* Uv = smem + 8192;
    unsigned char* Up = smem + 16384;
    _Float16*      spL = (_Float16*)(smem + 24576);      // stride 136 f16
    float*         afT = (float*)(smem + 41984);         // stride 68 f32
    unsigned char* eiT = smem + 59392;                   // stride 68 B

    const int bid = blockIdx.x;
    const int b = bid & 7;                // XCD swizzle: all 4 h of (b,n0) co-XCD
    const int h = (bid >> 3) & 3;
    const int n0 = (bid >> 5) * 64;
    const int l = threadIdx.x, lane = l & 63, w = l >> 6;
    const int wrow = w & 3, mhalf = w >> 2;
    const int grp = lane >> 4, col16 = lane & 15;

    // ---- init: stage q' (pre-scaled f16) and emb slice (f32 -> f16) ----
    {
        int row = l >> 3, sl = l & 7;
        i32x4 v = *(const i32x4*)(Qi + (size_t)(b * Nn + n0 + row) * Dd + h * 64 + sl * 8);
        *(i32x4*)(Uk + swz(row, sl * 16)) = v;
    }
#pragma unroll
    for (int it = 0; it < 2; ++it) {
        int s = l + it * 512, p = s >> 3, sl = s & 7;
        unsigned char* dst = (p < 64) ? (Uv + swz(p, sl * 16)) : (Up + swz(p - 64, sl * 16));
        stage8_f32(emb + (size_t)p * Dd + h * 64 + sl * 8, dst);
    }
    // kmask bitmask for this thread's 32 (mt,t) m-positions
    unsigned kbits = 0;
    for (int mt = 0; mt < 16; ++mt)
#pragma unroll
        for (int t = 0; t < 2; ++t) {
            int m = mt * 64 + mhalf * 32 + t * 16 + col16;
            kbits |= (kmask[b * Mm + m] ? 1u : 0u) << (mt * 2 + t);
        }
    __syncthreads();

    // q fragments held in registers for the whole kernel
    const int qrow = wrow * 16 + col16;
    f16x8 qf0 = *(const f16x8*)(Uk + swz(qrow, grp * 16));
    f16x8 qf1 = *(const f16x8*)(Uk + swz(qrow, grp * 16 + 64));

    // ---- positional scores: spL[r][p] = q'[r].emb_bank[h][p]; wave covers
    //      its 16 rows x its 64-p half ----
    {
        const unsigned char* ebase = mhalf ? Up : Uv;
#pragma unroll
        for (int t = 0; t < 4; ++t) {
            int pr = t * 16 + col16;
            f16x8 e0 = *(const f16x8*)(ebase + swz(pr, grp * 16));
            f16x8 e1 = *(const f16x8*)(ebase + swz(pr, grp * 16 + 64));
            f32x4 a = {};
            a = MFMA16(qf0, e0, a);
            a = MFMA16(qf1, e1, a);
#pragma unroll
            for (int j = 0; j < 4; ++j)
                spL[(wrow * 16 + grp * 4 + j) * 136 + mhalf * 64 + t * 16 + col16] = (_Float16)a[j];
        }
    }
    __syncthreads();

    const size_t afrow0 = (size_t)b * Nn * Mm + (size_t)n0 * Mm;
    const _Float16* Kb = Ki + (size_t)b * Mm * Dd + h * 64;
    const _Float16* Vb = Vt + (size_t)((b * Hh + h) * 64) * Mm;
    float* attnB = attn + (size_t)((b * Hh + h) * Nn + n0) * Mm;

    const int krowS = l >> 3, slS = l & 7;

#define LOADK(i_)  (*(const i32x4*)(Kb + (size_t)((i_) * 64 + krowS) * Dd + slS * 8))
#define LOADV(i_)  (*(const i32x4*)(Vb + (size_t)krowS * Mm + (i_) * 64 + slS * 8))
#define WRITEK(r_) { *(i32x4*)(Uk + swz(krowS, slS * 16)) = (r_); }
#define WRITEV(r_) { *(i32x4*)(Uv + swz(krowS, slS * 16)) = (r_); }
#define LOADAFEI(i_, afR, eiR) { \
    for (int it = 0; it < 2; ++it) { \
        int s = l + it * 512, row = s >> 4, q4 = s & 15; \
        size_t g = afrow0 + (size_t)row * Mm + (size_t)(i_) * 64 + q4 * 4; \
        afR[it] = *(const f32x4*)(afac + g); \
        i32x4 iv = *(const i32x4*)(eidx + g); \
        eiR[it] = (unsigned)(iv[0] & 255) | ((unsigned)(iv[1] & 255) << 8) \
                | ((unsigned)(iv[2] & 255) << 16) | ((unsigned)(iv[3] & 255) << 24); \
    } }
#define WRITEAFEI(afR, eiR) { \
    for (int it = 0; it < 2; ++it) { \
        int s = l + it * 512, row = s >> 4, q4 = s & 15; \
        *(f32x4*)(afT + row * 68 + q4 * 4) = afR[it]; \
        *(unsigned*)(eiT + row * 68 + q4 * 4) = eiR[it]; \
    } }

#define COMPUTE_A(mt_) { \
    __builtin_amdgcn_s_setprio(1); \
    f32x4 sc[2]; \
    _Pragma("unroll") for (int t = 0; t < 2; ++t) { \
        int krow = mhalf * 32 + t * 16 + col16; \
        f16x8 k0 = *(const f16x8*)(Uk + swz(krow, grp * 16)); \
        f16x8 k1 = *(const f16x8*)(Uk + swz(krow, grp * 16 + 64)); \
        f32x4 a = {}; a = MFMA16(qf0, k0, a); a = MFMA16(qf1, k1, a); sc[t] = a; \
    } \
    __builtin_amdgcn_s_setprio(0); \
    _Pragma("unroll") for (int t = 0; t < 2; ++t) { \
        int m = mhalf * 32 + t * 16 + col16; \
        _Pragma("unroll") for (int j = 0; j < 4; ++j) { \
            int rl = wrow * 16 + grp * 4 + j; \
            float sp = (float)spL[rl * 136 + eiT[rl * 68 + m]]; \
            float s = (sc[t][j] + sp) * afT[rl * 68 + m]; \
            float e = ((kbits >> ((mt_) * 2 + t)) & 1) ? 0.f : __expf(s); \
            sum_[j] += e; \
        } } }

#define COMPUTE_B(mt_) { \
    __builtin_amdgcn_s_setprio(1); \
    f32x4 sc[2]; \
    _Pragma("unroll") for (int t = 0; t < 2; ++t) { \
        int krow = mhalf * 32 + t * 16 + col16; \
        f16x8 k0 = *(const f16x8*)(Uk + swz(krow, grp * 16)); \
        f16x8 k1 = *(const f16x8*)(Uk + swz(krow, grp * 16 + 64)); \
        f32x4 a = {}; a = MFMA16(qf0, k0, a); a = MFMA16(qf1, k1, a); sc[t] = a; \
    } \
    __builtin_amdgcn_s_setprio(0); \
    _Pragma("unroll") for (int t = 0; t < 2; ++t) { \
        int m = mhalf * 32 + t * 16 + col16; \
        _Pragma("unroll") for (int j = 0; j < 4; ++j) { \
            int rl = wrow * 16 + grp * 4 + j; \
            float sp = (float)spL[rl * 136 + eiT[rl * 68 + m]]; \
            float s = (sc[t][j] + sp) * afT[rl * 68 + m]; \
            float e = ((kbits >> ((mt_) * 2 + t)) & 1) ? 0.f : __expf(s); \
            float p = e * rinv[j]; \
            attnB[(size_t)rl * Mm + (mt_) * 64 + m] = p; \
            *(_Float16*)(Up + swz(rl, m * 2)) = (_Float16)p; \
        } } \
    asm volatile("s_waitcnt lgkmcnt(0)" ::: "memory"); \
    __builtin_amdgcn_sched_barrier(0); \
    __builtin_amdgcn_s_setprio(1); \
    { const int prow = wrow * 16 + col16; \
      f16x8 pf = *(const f16x8*)(Up + swz(prow, mhalf * 64 + grp * 16)); \
      _Pragma("unroll") for (int t = 0; t < 4; ++t) { \
          int vrow = t * 16 + col16; \
          f16x8 vf = *(const f16x8*)(Uv + swz(vrow, mhalf * 64 + grp * 16)); \
          pv[t] = MFMA16(pf, vf, pv[t]); \
      } } \
    __builtin_amdgcn_s_setprio(0); }

    float sum_[4] = {0.f, 0.f, 0.f, 0.f};
    i32x4 kA, kB, vA, vB;
    f32x4 afA[2], afB[2];
    unsigned eiA[2], eiB[2];

    // =================== pass A: row sums of exp(s) ===================
    kA = LOADK(0); LOADAFEI(0, afA, eiA);
    kB = LOADK(1); LOADAFEI(1, afB, eiB);
    WRITEK(kA); WRITEAFEI(afA, eiA);
    __syncthreads();
    for (int mt = 0; mt < 16; mt += 2) {
        int n2 = (mt + 2 < 16) ? mt + 2 : 15;
        kA = LOADK(n2); LOADAFEI(n2, afA, eiA);
        COMPUTE_A(mt);
        __syncthreads();
        WRITEK(kB); WRITEAFEI(afB, eiB);
        __syncthreads();
        int n3 = (mt + 3 < 16) ? mt + 3 : 15;
        kB = LOADK(n3); LOADAFEI(n3, afB, eiB);
        COMPUTE_A(mt + 1);
        __syncthreads();
        WRITEK(kA); WRITEAFEI(afA, eiA);
        __syncthreads();
    }

    // ---- row sums: intra-16-lane shuffle + cross-m-half combine via LDS ----
    float rinv[4];
    {
        float* rs = (float*)Up;       // [2][64] f32, Up is free here
#pragma unroll
        for (int j = 0; j < 4; ++j) {
            float s_ = sum_[j];
#pragma unroll
            for (int d = 1; d < 16; d <<= 1) s_ += __shfl_xor(s_, d, 16);
            if (col16 == 0) rs[mhalf * 64 + wrow * 16 + grp * 4 + j] = s_;
        }
        __syncthreads();
#pragma unroll
        for (int j = 0; j < 4; ++j) {
            int rl = wrow * 16 + grp * 4 + j;
            float tot = rs[rl] + rs[64 + rl];
            rinv[j] = (tot > 0.f) ? (1.f / tot) : 0.f;
        }
    }

    // ========== pass B: p = exp(s)*rinv -> attn write + PV ==========
    f32x4 pv[4] = {};
    kA = LOADK(0); vA = LOADV(0); LOADAFEI(0, afA, eiA);
    kB = LOADK(1); vB = LOADV(1); LOADAFEI(1, afB, eiB);
    WRITEK(kA); WRITEV(vA); WRITEAFEI(afA, eiA);
    __syncthreads();
    for (int mt = 0; mt < 16; mt += 2) {
        int n2 = (mt + 2 < 16) ? mt + 2 : 15;
        kA = LOADK(n2); vA = LOADV(n2); LOADAFEI(n2, afA, eiA);
        COMPUTE_B(mt);
        __syncthreads();
        WRITEK(kB); WRITEV(vB); WRITEAFEI(afB, eiB);
        __syncthreads();
        int n3 = (mt + 3 < 16) ? mt + 3 : 15;
        kB = LOADK(n3); vB = LOADV(n3); LOADAFEI(n3, afB, eiB);
        COMPUTE_B(mt + 1);
        __syncthreads();
        WRITEK(kA); WRITEV(vA); WRITEAFEI(afA, eiA);
        __syncthreads();
    }

    // ---- hidden: combine m-halves via LDS, waves mhalf==0 write out ----
    {
        float* pvx = (float*)smem;    // [64][68] f32 overlay
        if (mhalf == 1) {
#pragma unroll
            for (int t = 0; t < 4; ++t)
#pragma unroll
                for (int j = 0; j < 4; ++j)
                    pvx[(wrow * 16 + grp * 4 + j) * 68 + t * 16 + col16] = pv[t][j];
        }
        __syncthreads();
        if (mhalf == 0) {
#pragma unroll
            for (int t = 0; t < 4; ++t)
#pragma unroll
                for (int j = 0; j < 4; ++j) {
                    int rl = wrow * 16 + grp * 4 + j;
                    int n = n0 + rl;
                    hid[(size_t)(b * Nn + n) * Dd + h * 64 + t * 16 + col16] =
                        pv[t][j] + pvx[rl * 68 + t * 16 + col16];
                }
        }
    }
#undef LOADK
#undef LOADV
#undef WRITEK
#undef WRITEV
#undef LOADAFEI
#undef WRITEAFEI
#undef COMPUTE_A
#undef COMPUTE_B
}

// ---------------------------------------------------------------------------
extern "C" void kernel_launch(void* const* d_in, const int* in_sizes, int n_in,
                              void* d_out, int out_size, void* d_ws, size_t ws_size,
                              hipStream_t stream)
{
    (void)in_sizes; (void)n_in; (void)out_size; (void)ws_size;

    const float* xq   = (const float*)d_in[0];
    const float* xk   = (const float*)d_in[1];
    const float* xv   = (const float*)d_in[2];
    const float* wq   = (const float*)d_in[3];
    const float* bq   = (const float*)d_in[4];
    const float* wk   = (const float*)d_in[5];
    const float* bk   = (const float*)d_in[6];
    const float* wv   = (const float*)d_in[7];
    const float* bv   = (const float*)d_in[8];
    const float* emb  = (const float*)d_in[9];
    const float* afac = (const float*)d_in[10];
    const int*   eidx = (const int*)d_in[11];
    const unsigned char* kmask = (const unsigned char*)d_in[12];

    _Float16* Q  = (_Float16*)d_ws;                 // [8192][256] f16 (pre-scaled 0.125)
    _Float16* K  = Q + (size_t)8192 * 256;          // [8192][256] f16
    _Float16* Vt = K + (size_t)8192 * 256;          // [(b,h,c)][1024] f16 (transposed V)

    float* hid  = (float*)d_out;                    // (B, N, D)
    float* attn = hid + (size_t)Bb * Nn * Dd;       // (B, H, N, M)

    proj_kernel<<<dim3(64, 4, 3), 256, 0, stream>>>(xq, xk, xv, wq, wk, wv,
                                                    bq, bk, bv, Q, K, Vt);
    attn_kernel<<<512, 512, 0, stream>>>(Q, K, Vt, emb, afac, eidx,
                                         kmask, hid, attn);
}